// Round 1
// baseline (201.793 us; speedup 1.0000x reference)
//
#include <hip/hip_runtime.h>

// ---------------------------------------------------------------------------
// QuantizedShaper: B=256, L=8192, DIM=256, NPAT=64, HIST=32, WIN=8, T=1024.
//
// Key algebraic fusions:
//   scores[t,b,p] = clip( sum_h xpad[b, t*8+h] * W2[p,h] + bias2[p], 0, 6 )
//     where W2[p,h] = sum_d keys_w[p,d]*conv_w[d,0,h], bias2[p] = keys.conv_b
//   out[b, t*8+w] = relu( shapes_w[w, idx[t,b]] - x[b, t*8+w] )   (exact: one-hot)
//
// Mapping: one block per batch element b (256 blocks = 256 CUs).
//   wave 0  : sequential scan (lane = pattern p), DPP argmax per step
//   waves1-3: score tiles for chunk c+1 while wave0 scans chunk c (dbuf LDS)
// ---------------------------------------------------------------------------

constexpr int Bb = 256, Ll = 8192, DIMc = 256, NPAT = 64, HIST = 32, WINc = 8;
constexpr int Tt = Ll / WINc;   // 1024
constexpr int TC = 32;          // t-chunk
constexpr int NC = Tt / TC;     // 32 chunks

// one fused dpp-max step (ctrl/masks must be literals)
#define DPP_MAXF(m, ctrl, rmask)                                               \
  do {                                                                         \
    int _mi = __float_as_int(m);                                               \
    int _ti = __builtin_amdgcn_update_dpp(_mi, _mi, (ctrl), (rmask), 0xF, false); \
    (m) = fmaxf((m), __int_as_float(_ti));                                     \
  } while (0)

__global__ void precompute_kernel(const float* __restrict__ conv_w,
                                  const float* __restrict__ conv_b,
                                  const float* __restrict__ keys_w,
                                  float* __restrict__ wsf) {
  int gid = blockIdx.x * blockDim.x + threadIdx.x;
  if (gid < NPAT * HIST) {
    int p = gid >> 5, h = gid & 31;
    float acc = 0.f;
    for (int d = 0; d < DIMc; ++d)
      acc = fmaf(keys_w[p * DIMc + d], conv_w[d * HIST + h], acc);
    // layout: float4-friendly [h4][p][h%4]
    wsf[(h >> 2) * (NPAT * 4) + p * 4 + (h & 3)] = acc;
  } else if (gid < NPAT * HIST + NPAT) {
    int p = gid - NPAT * HIST;
    float acc = 0.f;
    for (int d = 0; d < DIMc; ++d)
      acc = fmaf(keys_w[p * DIMc + d], conv_b[d], acc);
    wsf[NPAT * HIST + p] = acc;
  }
}

__global__ __launch_bounds__(256) void shaper_kernel(
    const float* __restrict__ x, const float* __restrict__ avg_init,
    const float* __restrict__ shapes_w, const float* __restrict__ wsf,
    float* __restrict__ out) {
  __shared__ __align__(16) float xpad[HIST - 1 + Ll + 1];  // left zero-pad: aligned windows
  __shared__ float scb[2][TC * NPAT];
  __shared__ int   idxb[Tt];
  __shared__ float shp[WINc * NPAT];

  const int b    = blockIdx.x;
  const int tid  = threadIdx.x;
  const int wid  = tid >> 6;
  const int lane = tid & 63;
  const float* xrow = x + (size_t)b * Ll;

  // ---- stage x (left-padded) + shapes into LDS ----
  if (tid < HIST - 1) xpad[tid] = 0.f;
  for (int i = tid; i < Ll; i += 256) xpad[HIST - 1 + i] = xrow[i];
  for (int i = tid; i < WINc * NPAT; i += 256) shp[i] = shapes_w[i];

  // ---- per-role register setup ----
  float4 w2v[8];
  float  b2 = 0.f;
  if (wid > 0) {
    const float4* w2g = (const float4*)wsf;
#pragma unroll
    for (int h4 = 0; h4 < 8; ++h4) w2v[h4] = w2g[h4 * 64 + lane];
    b2 = wsf[NPAT * HIST + lane];
  }
  float av = 0.f;
  if (wid == 0) {
    const float* ai = avg_init + (size_t)b * NPAT;
    float s = 0.f;
    for (int j = 0; j < NPAT; ++j) s += ai[j];
    av = ai[lane] - s * (1.0f / NPAT);  // avg0 = avg_init - mean
  }
  __syncthreads();

  // score tile fill for chunk c (waves 1..3)
  auto fill = [&](int c, float* __restrict__ sb) {
    int base = c * TC;
    for (int tl = wid - 1; tl < TC; tl += 3) {
      int t = base + tl;
      const float4* xw = (const float4*)(xpad + t * WINc);  // 32B offset -> aligned
      float acc = b2;
#pragma unroll
      for (int h4 = 0; h4 < 8; ++h4) {
        float4 xv = xw[h4];
        float4 wv = w2v[h4];
        acc = fmaf(xv.x, wv.x, acc);
        acc = fmaf(xv.y, wv.y, acc);
        acc = fmaf(xv.z, wv.z, acc);
        acc = fmaf(xv.w, wv.w, acc);
      }
      float sc = fminf(fmaxf(acc, 0.f), 6.f);  // relu6, exact clip
      sb[tl * NPAT + lane] = sc;
    }
  };

  // 16 sequential scan steps from register-resident scores
  auto scan16 = [&](const float* r, int tbase) {
#pragma unroll
    for (int i = 0; i < 16; ++i) {
      float v = r[i] - av;
      float m = v;
      DPP_MAXF(m, 0xB1, 0xF);   // xor1  (quad_perm 1,0,3,2)
      DPP_MAXF(m, 0x4E, 0xF);   // xor2  (quad_perm 2,3,0,1)
      DPP_MAXF(m, 0x141, 0xF);  // xor4  (row_half_mirror)
      DPP_MAXF(m, 0x140, 0xF);  // xor8  (row_mirror)       -> row(16) max
      DPP_MAXF(m, 0x142, 0xA);  // row_bcast15 into rows 1,3
      DPP_MAXF(m, 0x143, 0xC);  // row_bcast31 into rows 2,3 -> lane63 = global max
      float gmax = __int_as_float(
          __builtin_amdgcn_readlane(__float_as_int(m), 63));
      unsigned long long mk = __ballot(v == gmax);
      int winner = __ffsll(mk) - 1;  // first max index == jnp.argmax tie-break
      if (lane == 0) idxb[tbase + i] = winner;
      float prob = (lane == winner) ? 1.0f : 0.0f;
      av = (av + prob) - (1.0f / NPAT);  // mirror reference fp op order
    }
  };

  // ---- software pipeline: wave0 scans chunk c, waves1-3 fill chunk c+1 ----
  if (wid > 0) fill(0, scb[0]);
  __syncthreads();

  for (int c = 0; c < NC; ++c) {
    if (wid == 0) {
      float* sb = scb[c & 1];
      float r0[16], r1[16];
#pragma unroll
      for (int i = 0; i < 16; ++i) r0[i] = sb[i * NPAT + lane];
#pragma unroll
      for (int i = 0; i < 16; ++i) r1[i] = sb[(16 + i) * NPAT + lane];
      scan16(r0, c * TC);
      scan16(r1, c * TC + 16);
    } else if (c + 1 < NC) {
      fill(c + 1, scb[(c + 1) & 1]);
    }
    __syncthreads();
  }

  // ---- epilogue: out[b,l] = relu(shapes[l&7, idx[l>>3]] - x[b,l]) ----
  float4* outv = (float4*)(out + (size_t)b * Ll);
#pragma unroll
  for (int k = 0; k < 8; ++k) {
    int i4 = k * 256 + tid;      // float4 index within row
    int l0 = i4 * 4;             // element index; (l0&7) in {0,4} -> same t for all 4
    int t  = l0 >> 3;
    int w0 = l0 & 7;
    int p  = idxb[t];
    float4 o;
    o.x = fmaxf(shp[(w0 + 0) * NPAT + p] - xpad[HIST - 1 + l0 + 0], 0.f);
    o.y = fmaxf(shp[(w0 + 1) * NPAT + p] - xpad[HIST - 1 + l0 + 1], 0.f);
    o.z = fmaxf(shp[(w0 + 2) * NPAT + p] - xpad[HIST - 1 + l0 + 2], 0.f);
    o.w = fmaxf(shp[(w0 + 3) * NPAT + p] - xpad[HIST - 1 + l0 + 3], 0.f);
    outv[i4] = o;
  }
}

extern "C" void kernel_launch(void* const* d_in, const int* in_sizes, int n_in,
                              void* d_out, int out_size, void* d_ws, size_t ws_size,
                              hipStream_t stream) {
  const float* x        = (const float*)d_in[0];
  const float* avg_init = (const float*)d_in[1];
  const float* conv_w   = (const float*)d_in[2];
  const float* conv_b   = (const float*)d_in[3];
  const float* keys_w   = (const float*)d_in[4];
  const float* shapes_w = (const float*)d_in[5];
  float* wsf = (float*)d_ws;

  precompute_kernel<<<9, 256, 0, stream>>>(conv_w, conv_b, keys_w, wsf);
  shaper_kernel<<<Bb, 256, 0, stream>>>(x, avg_init, shapes_w, wsf,
                                        (float*)d_out);
}

// Round 3
// 186.701 us; speedup vs baseline: 1.0808x; 1.0808x over previous
//
#include <hip/hip_runtime.h>

// ---------------------------------------------------------------------------
// QuantizedShaper: B=256, L=8192, DIM=256, NPAT=64, HIST=32, WIN=8, T=1024.
//
//   scores[t,b,p] = clip( sum_h xpad[b, t*8+h] * W2[p,h] + bias2[p], 0, 6 )
//     W2[p,h] = sum_d keys_w[p,d]*conv_w[d,0,h],  bias2[p] = keys(conv_b)
//   out[b, t*8+w] = relu( shapes_w[w, idx[t,b]] - x[b, t*8+w] )  (one-hot exact)
//
// One block per batch element (256 blocks = 256 CUs).
//   wave 0  : sequential balanced-routing scan, lane = pattern p.
//             Per step: DPP 6-stage max -> readlane -> ballot -> ffs.
//             av update + next v are SPECULATED (t0/t1, vA/vB) so the
//             dependent chain ends in two cndmasks (fp-identical to ref).
//   waves1-3: score tile for chunk c+1 while wave0 scans chunk c (dbuf LDS)
// ---------------------------------------------------------------------------

constexpr int Bb = 256, Ll = 8192, DIMc = 256, NPAT = 64, HIST = 32, WINc = 8;
constexpr int Tt = Ll / WINc;   // 1024
constexpr int TC = 32;          // t-chunk
constexpr int NC = Tt / TC;     // 32 chunks
constexpr float CINV = 1.0f / 64.0f;

#define DPP_MAXF(m, ctrl, rmask)                                               \
  do {                                                                         \
    int _mi = __float_as_int(m);                                               \
    int _ti = __builtin_amdgcn_update_dpp(_mi, _mi, (ctrl), (rmask), 0xF, false); \
    (m) = fmaxf((m), __int_as_float(_ti));                                     \
  } while (0)

// one block per pattern p: W2[p,0..31] + bias2[p]
__global__ __launch_bounds__(256) void precompute_kernel(
    const float* __restrict__ conv_w, const float* __restrict__ conv_b,
    const float* __restrict__ keys_w, float* __restrict__ wsf) {
  __shared__ float part[8][32];
  __shared__ float bred[4];
  const int p = blockIdx.x;
  const int t = threadIdx.x;
  const int h = t & 31, g = t >> 5;
  const float* kwp = keys_w + (size_t)p * DIMc;

  float acc = 0.f;
#pragma unroll
  for (int dd = 0; dd < 32; ++dd) {
    int d = g * 32 + dd;
    acc = fmaf(kwp[d], conv_w[d * HIST + h], acc);
  }
  part[g][h] = acc;

  float bp = kwp[t] * conv_b[t];
#pragma unroll
  for (int off = 32; off; off >>= 1) bp += __shfl_down(bp, off);
  if ((t & 63) == 0) bred[t >> 6] = bp;
  __syncthreads();

  if (t < 32) {
    float s = 0.f;
#pragma unroll
    for (int gg = 0; gg < 8; ++gg) s += part[gg][t];
    wsf[(t >> 2) * (NPAT * 4) + p * 4 + (t & 3)] = s;  // float4-friendly
  } else if (t == 32) {
    wsf[NPAT * HIST + p] = (bred[0] + bred[1]) + (bred[2] + bred[3]);
  }
}

__global__ __launch_bounds__(256) void shaper_kernel(
    const float* __restrict__ x, const float* __restrict__ avg_init,
    const float* __restrict__ shapes_w, const float* __restrict__ wsf,
    float* __restrict__ out) {
  __shared__ __align__(16) float xpad[HIST - 1 + Ll + 1];
  __shared__ float scb[2][TC * NPAT];
  __shared__ int   idxb[Tt];
  __shared__ float shp[WINc * NPAT];

  const int b    = blockIdx.x;
  const int tid  = threadIdx.x;
  const int wid  = tid >> 6;
  const int lane = tid & 63;
  const float* xrow = x + (size_t)b * Ll;

  // ---- stage x (left-padded) + shapes into LDS ----
  if (tid < HIST - 1) xpad[tid] = 0.f;
  {
    const float4* xv4 = (const float4*)xrow;
#pragma unroll
    for (int k = 0; k < 8; ++k) {
      int i4 = k * 256 + tid;
      float4 v = xv4[i4];
      float* dst = xpad + HIST - 1 + i4 * 4;
      dst[0] = v.x; dst[1] = v.y; dst[2] = v.z; dst[3] = v.w;
    }
  }
  for (int i = tid; i < WINc * NPAT; i += 256) shp[i] = shapes_w[i];

  // ---- per-role setup ----
  float4 w2v[8];
  float  b2 = 0.f;
  if (wid > 0) {
    const float4* w2g = (const float4*)wsf;
#pragma unroll
    for (int h4 = 0; h4 < 8; ++h4) w2v[h4] = w2g[h4 * 64 + lane];
    b2 = wsf[NPAT * HIST + lane];
  }
  float av = 0.f;
  if (wid == 0) {
    const float* ai = avg_init + (size_t)b * NPAT;
    float s = 0.f;
    for (int j = 0; j < NPAT; ++j) s += ai[j];
    av = ai[lane] - s * (1.0f / NPAT);  // avg0 = avg_init - mean
  }
  __syncthreads();

  // score tile for chunk c (waves 1..3)
  auto fill = [&](int c, float* __restrict__ sb) {
    int base = c * TC;
    for (int tl = wid - 1; tl < TC; tl += 3) {
      int t = base + tl;
      const float4* xw = (const float4*)(xpad + t * WINc);  // 32B-aligned
      float acc = b2;
#pragma unroll
      for (int h4 = 0; h4 < 8; ++h4) {
        float4 xv = xw[h4];
        float4 wv = w2v[h4];
        acc = fmaf(xv.x, wv.x, acc);
        acc = fmaf(xv.y, wv.y, acc);
        acc = fmaf(xv.z, wv.z, acc);
        acc = fmaf(xv.w, wv.w, acc);
      }
      sb[tl * NPAT + lane] = fminf(fmaxf(acc, 0.f), 6.f);  // relu6
    }
  };

  // 32 sequential steps; speculative av / v-next so the dependent chain is
  // cndmask -> 6x max_dpp -> readlane -> cmp -> ff1 -> cmp -> cndmask.
  auto scan_chunk = [&](const float* __restrict__ sb, int tbase) {
    float r[TC];
#pragma unroll
    for (int i = 0; i < TC; ++i) r[i] = sb[i * NPAT + lane];
    float v = r[0] - av;
    int stash = 0;
#pragma unroll
    for (int i = 0; i < TC; ++i) {
      float t0 = av - CINV;            // == (av + 0.0f) - 1/64 exactly
      float t1 = (av + 1.0f) - CINV;   // winner path, reference fp order
      float vA = 0.f, vB = 0.f;
      if (i + 1 < TC) { vA = r[i + 1] - t0; vB = r[i + 1] - t1; }
      float m = v;
      DPP_MAXF(m, 0xB1, 0xF);   // quad_perm 1,0,3,2  (xor1)
      DPP_MAXF(m, 0x4E, 0xF);   // quad_perm 2,3,0,1  (xor2)
      DPP_MAXF(m, 0x141, 0xF);  // row_half_mirror
      DPP_MAXF(m, 0x140, 0xF);  // row_mirror         -> row(16) max
      DPP_MAXF(m, 0x142, 0xA);  // row_bcast15 -> rows 1,3
      DPP_MAXF(m, 0x143, 0xC);  // row_bcast31 -> rows 2,3; lane63 = gmax
      float gmax = __int_as_float(
          __builtin_amdgcn_readlane(__float_as_int(m), 63));
      unsigned long long mk = __ballot(v == gmax);
      int winner = __ffsll(mk) - 1;           // first-index tie-break
      // branchless per-lane stash of this step's winner (off the dep chain)
      stash = (lane == i) ? winner : stash;
      bool win = (lane == winner);
      av = win ? t1 : t0;
      if (i + 1 < TC) v = win ? vB : vA;
    }
    if (lane < TC) idxb[tbase + lane] = stash;
  };

  // ---- pipeline: wave0 scans chunk c, waves1-3 fill chunk c+1 ----
  if (wid > 0) fill(0, scb[0]);
  __syncthreads();

  for (int c = 0; c < NC; ++c) {
    if (wid == 0) {
      scan_chunk(scb[c & 1], c * TC);
    } else if (c + 1 < NC) {
      fill(c + 1, scb[(c + 1) & 1]);
    }
    __syncthreads();
  }

  // ---- epilogue: out[b,l] = relu(shapes[l&7, idx[l>>3]] - x[b,l]) ----
  float4* outv = (float4*)(out + (size_t)b * Ll);
#pragma unroll
  for (int k = 0; k < 8; ++k) {
    int i4 = k * 256 + tid;
    int l0 = i4 * 4;
    int t  = l0 >> 3;
    int w0 = l0 & 7;
    int p  = idxb[t];
    float4 o;
    o.x = fmaxf(shp[(w0 + 0) * NPAT + p] - xpad[HIST - 1 + l0 + 0], 0.f);
    o.y = fmaxf(shp[(w0 + 1) * NPAT + p] - xpad[HIST - 1 + l0 + 1], 0.f);
    o.z = fmaxf(shp[(w0 + 2) * NPAT + p] - xpad[HIST - 1 + l0 + 2], 0.f);
    o.w = fmaxf(shp[(w0 + 3) * NPAT + p] - xpad[HIST - 1 + l0 + 3], 0.f);
    outv[i4] = o;
  }
}

extern "C" void kernel_launch(void* const* d_in, const int* in_sizes, int n_in,
                              void* d_out, int out_size, void* d_ws, size_t ws_size,
                              hipStream_t stream) {
  const float* x        = (const float*)d_in[0];
  const float* avg_init = (const float*)d_in[1];
  const float* conv_w   = (const float*)d_in[2];
  const float* conv_b   = (const float*)d_in[3];
  const float* keys_w   = (const float*)d_in[4];
  const float* shapes_w = (const float*)d_in[5];
  float* wsf = (float*)d_ws;

  precompute_kernel<<<NPAT, 256, 0, stream>>>(conv_w, conv_b, keys_w, wsf);
  shaper_kernel<<<Bb, 256, 0, stream>>>(x, avg_init, shapes_w, wsf,
                                        (float*)d_out);
}